// Round 2
// baseline (403.789 us; speedup 1.0000x reference)
//
#include <hip/hip_runtime.h>

// Wilson-Cowan-like rate recurrence.
//   u       = E[b,t,n] - r[n]*nu
//   phi(u)  = M[n]*u/(u^2+sigma[n]^2) * relu(u+th[n])
//   nu     += (DT/tau_nu[n]) * (phi(u) - nu)
// Serial over t, independent over (b,n). 8*1024 = 8192 sequences.

#define DT_STEP 0.1f

constexpr int Bc = 8;
constexpr int Tc = 4096;
constexpr int Nc = 1024;
constexpr int UNROLL = 32;   // prefetch depth: 32 loads in flight/lane = 8 KiB/wave

__global__ __launch_bounds__(64, 1) void cw_recurrence_kernel(
    const float* __restrict__ E,
    const float* __restrict__ r,
    const float* __restrict__ tau_nu,
    const float* __restrict__ M,
    const float* __restrict__ sigma,
    const float* __restrict__ th,
    float* __restrict__ out)
{
    const int idx = blockIdx.x * 64 + threadIdx.x;   // 0..8191
    const int b = idx >> 10;                         // idx / N
    const int n = idx & (Nc - 1);                    // idx % N

    const float rv   = r[n];
    const float coef = DT_STEP / tau_nu[n];          // once per thread; exact div ok
    const float Mv   = M[n];
    const float sv   = sigma[n];
    const float s2   = sv * sv;
    const float thv  = th[n];

    const float* __restrict__ Ep = E   + (size_t)b * Tc * Nc + n;
    float*       __restrict__ Op = out + (size_t)b * Tc * Nc + n;

    float nu = 0.0f;

    // Software pipeline: register ring of UNROLL prefetched E values.
    float ebuf[UNROLL];
#pragma unroll
    for (int j = 0; j < UNROLL; ++j)
        ebuf[j] = Ep[(size_t)j * Nc];

    for (int tc = 0; tc < Tc; tc += UNROLL) {
        float enext[UNROLL];
        const bool more = (tc + UNROLL) < Tc;
        if (more) {
#pragma unroll
            for (int j = 0; j < UNROLL; ++j)
                enext[j] = Ep[(size_t)(tc + UNROLL + j) * Nc];
        }

#pragma unroll
        for (int j = 0; j < UNROLL; ++j) {
            const float e   = ebuf[j];
            const float u   = fmaf(-rv, nu, e);            // E - r*nu
            const float d   = fmaf(u, u, s2);              // u^2 + sigma^2
            const float inv = __builtin_amdgcn_rcpf(d);    // v_rcp_f32 (approx, ok vs 1e-2 thr)
            const float g   = fmaxf(u + thv, 0.0f);        // relu(u+th)
            const float phi = (Mv * u) * (inv * g);
            nu = fmaf(coef, phi - nu, nu);                 // nu + coef*(phi-nu)
            Op[(size_t)(tc + j) * Nc] = nu;
        }

        if (more) {
#pragma unroll
            for (int j = 0; j < UNROLL; ++j)
                ebuf[j] = enext[j];
        }
    }
}

extern "C" void kernel_launch(void* const* d_in, const int* in_sizes, int n_in,
                              void* d_out, int out_size, void* d_ws, size_t ws_size,
                              hipStream_t stream) {
    const float* E      = (const float*)d_in[0];
    const float* r      = (const float*)d_in[1];
    const float* tau_nu = (const float*)d_in[2];
    const float* M      = (const float*)d_in[3];
    const float* sigma  = (const float*)d_in[4];
    const float* th     = (const float*)d_in[5];
    float* out = (float*)d_out;

    const int total  = Bc * Nc;          // 8192 independent sequences
    const int block  = 64;               // 1 wave per block -> spread over CUs
    const int grid   = total / block;    // 128 blocks

    cw_recurrence_kernel<<<grid, block, 0, stream>>>(E, r, tau_nu, M, sigma, th, out);
}

// Round 3
// 306.197 us; speedup vs baseline: 1.3187x; 1.3187x over previous
//
#include <hip/hip_runtime.h>

// Wilson-Cowan-like rate recurrence, latency-pipelined version.
//   u       = E[b,t,n] - r[n]*nu
//   phi(u)  = M[n]*u/(u^2+sigma[n]^2) * relu(u+th[n])
//   nu     += (DT/tau_nu[n]) * (phi(u) - nu)
// 8192 independent serial chains (b,n), T=4096 steps.
//
// Round-2 evidence: compiler collapsed the source-level prefetch ring
// (VGPR=44, ~3 loads in flight/wave, 142 cyc/step). Fix: explicit ring of
// D=32 inline-asm global_load_dword with counted s_waitcnt vmcnt(K).
// vmcnt is in-order and counts stores too (gfx9 lineage), so
// K = #vmem ops issued after the load being waited on:
//   head block (j=0..31):  K = 31+j   (prologue issued 32 loads)
//   steady blocks:         K = 62     (31 loads + 31 stores newer)
//   tail block (j=0..31):  K = 62-j   (no loads issued in tail)
// The wait asm ties the buffer register ("+v") so the dependent compute
// cannot be hoisted above it (ERRATA #18 analog).

#define DT_STEP 0.1f

constexpr int Bc = 8;
constexpr int Tc = 4096;
constexpr int Nc = 1024;
constexpr int D  = 32;   // loads in flight per lane; 32*256B = 8KiB/wave

__global__ __launch_bounds__(64, 1) void cw_recurrence_kernel(
    const float* __restrict__ E,
    const float* __restrict__ r,
    const float* __restrict__ tau_nu,
    const float* __restrict__ M,
    const float* __restrict__ sigma,
    const float* __restrict__ th,
    float* __restrict__ out)
{
    const int idx = blockIdx.x * 64 + threadIdx.x;   // 0..8191
    const int b = idx >> 10;
    const int n = idx & (Nc - 1);

    const float rv   = r[n];
    const float coef = DT_STEP / tau_nu[n];
    const float Mv   = M[n];
    const float sv   = sigma[n];
    const float s2   = sv * sv;
    const float thv  = th[n];

    const float* lp = E   + (size_t)b * Tc * Nc + n;   // load pointer (advances Nc/step)
    float*       sp = out + (size_t)b * Tc * Nc + n;   // store pointer

    float nu = 0.0f;
    float buf[D];

    // ---- prologue: issue D loads (t = 0..31), no waits ----
#pragma unroll
    for (int j = 0; j < D; ++j) {
        asm volatile("global_load_dword %0, %1, off" : "=v"(buf[j]) : "v"(lp));
        lp += Nc;
    }

#define WAITK(K, slot) asm volatile("s_waitcnt vmcnt(" #K ")" : "+v"(buf[slot]))
#define BODY(slot) do {                                                  \
        float e   = buf[slot];                                           \
        float u   = fmaf(-rv, nu, e);                                    \
        float dd  = fmaf(u, u, s2);                                      \
        float inv = __builtin_amdgcn_rcpf(dd);                           \
        float g   = fmaxf(u + thv, 0.0f);                                \
        float phi = (Mv * u) * (inv * g);                                \
        nu = fmaf(coef, phi - nu, nu);                                   \
        asm volatile("global_store_dword %0, %1, off" :: "v"(sp), "v"(nu)); \
        sp += Nc;                                                        \
    } while (0)
#define LOADQ(slot) do {                                                 \
        asm volatile("global_load_dword %0, %1, off" : "=v"(buf[slot]) : "v"(lp)); \
        lp += Nc;                                                        \
    } while (0)

#define SHEAD(j, K) WAITK(K, j); BODY(j); LOADQ(j);
#define SMAIN(j)    WAITK(62, j); BODY(j); LOADQ(j);
#define STAIL(j, K) WAITK(K, j); BODY(j);

    // ---- block 0 (t=0..31): issues loads for block 1; K ramps 31->62 ----
    SHEAD(0,31)  SHEAD(1,32)  SHEAD(2,33)  SHEAD(3,34)
    SHEAD(4,35)  SHEAD(5,36)  SHEAD(6,37)  SHEAD(7,38)
    SHEAD(8,39)  SHEAD(9,40)  SHEAD(10,41) SHEAD(11,42)
    SHEAD(12,43) SHEAD(13,44) SHEAD(14,45) SHEAD(15,46)
    SHEAD(16,47) SHEAD(17,48) SHEAD(18,49) SHEAD(19,50)
    SHEAD(20,51) SHEAD(21,52) SHEAD(22,53) SHEAD(23,54)
    SHEAD(24,55) SHEAD(25,56) SHEAD(26,57) SHEAD(27,58)
    SHEAD(28,59) SHEAD(29,60) SHEAD(30,61) SHEAD(31,62)

    // ---- steady blocks k = 1..126 (t=32..4063): uniform K=62 ----
    for (int k = 1; k <= 126; ++k) {
        SMAIN(0)  SMAIN(1)  SMAIN(2)  SMAIN(3)
        SMAIN(4)  SMAIN(5)  SMAIN(6)  SMAIN(7)
        SMAIN(8)  SMAIN(9)  SMAIN(10) SMAIN(11)
        SMAIN(12) SMAIN(13) SMAIN(14) SMAIN(15)
        SMAIN(16) SMAIN(17) SMAIN(18) SMAIN(19)
        SMAIN(20) SMAIN(21) SMAIN(22) SMAIN(23)
        SMAIN(24) SMAIN(25) SMAIN(26) SMAIN(27)
        SMAIN(28) SMAIN(29) SMAIN(30) SMAIN(31)
    }

    // ---- tail block (t=4064..4095): no loads; K ramps 62->31 ----
    STAIL(0,62)  STAIL(1,61)  STAIL(2,60)  STAIL(3,59)
    STAIL(4,58)  STAIL(5,57)  STAIL(6,56)  STAIL(7,55)
    STAIL(8,54)  STAIL(9,53)  STAIL(10,52) STAIL(11,51)
    STAIL(12,50) STAIL(13,49) STAIL(14,48) STAIL(15,47)
    STAIL(16,46) STAIL(17,45) STAIL(18,44) STAIL(19,43)
    STAIL(20,42) STAIL(21,41) STAIL(22,40) STAIL(23,39)
    STAIL(24,38) STAIL(25,37) STAIL(26,36) STAIL(27,35)
    STAIL(28,34) STAIL(29,33) STAIL(30,32) STAIL(31,31)

#undef WAITK
#undef BODY
#undef LOADQ
#undef SHEAD
#undef SMAIN
#undef STAIL
}

extern "C" void kernel_launch(void* const* d_in, const int* in_sizes, int n_in,
                              void* d_out, int out_size, void* d_ws, size_t ws_size,
                              hipStream_t stream) {
    const float* E      = (const float*)d_in[0];
    const float* r      = (const float*)d_in[1];
    const float* tau_nu = (const float*)d_in[2];
    const float* M      = (const float*)d_in[3];
    const float* sigma  = (const float*)d_in[4];
    const float* th     = (const float*)d_in[5];
    float* out = (float*)d_out;

    const int total = Bc * Nc;        // 8192 independent sequences
    const int block = 64;             // 1 wave per block
    const int grid  = total / block;  // 128 blocks

    cw_recurrence_kernel<<<grid, block, 0, stream>>>(E, r, tau_nu, M, sigma, th, out);
}